// Round 12
// baseline (2356.280 us; speedup 1.0000x reference)
//
#include <hip/hip_runtime.h>
#include <math.h>

#define TPQ 60
#define TPP 400
#define BB  16
#define II  256
#define HH  256

typedef short bf16x8 __attribute__((ext_vector_type(8)));
typedef float f32x4  __attribute__((ext_vector_type(4)));
typedef unsigned short u16;

__device__ __forceinline__ float sigm(float x){ return 1.0f/(1.0f+__expf(-x)); }
__device__ __forceinline__ float tanhfast(float x){
  x = fminf(fmaxf(x,-20.0f),20.0f);
  float t = __expf(2.0f*x);
  return (t-1.0f)/(t+1.0f);
}
__device__ __forceinline__ short f2bf(float f){
  unsigned u = __float_as_uint(f);
  unsigned r = (u + 0x7fffu + ((u>>16)&1u)) >> 16;
  return (short)r;
}
__device__ __forceinline__ float bf2f(short h){
  return __uint_as_float(((unsigned)(unsigned short)h)<<16);
}

__global__ void f2bf_k(const float* __restrict__ src, u16* __restrict__ dst, int n){
  int i = blockIdx.x*256 + threadIdx.x;
  if (i < n) dst[i] = (u16)f2bf(src[i]);
}

// ---------------------------------------------------------------------------
// bf16 MFMA GEMM, A supplied as f32 and hi/lo-split during LDS staging:
//   C[M][N] = A[M][K] @ W[N][K]^T (+bias)   EP==1: C = msrc * sigmoid(C)
// tile 128x128, K-step 32, 256 threads (4 waves, 2x2 quadrants of 64x64).
// LDS in fragment order -> staging writes and fragment reads conflict-free.
// Requires N%128==0, K%32==0; M guarded.
// ---------------------------------------------------------------------------
template<int EP>
__global__ __launch_bounds__(256) void gemm_bf16_hl(
    const float* __restrict__ Af,   // [M][K] f32
    const u16* __restrict__ Wb,     // [N][K] bf16
    const float* __restrict__ bias, // [N]
    const float* __restrict__ msrc, // [M][N] (EP==1)
    float* __restrict__ C, int M, int N, int K)
{
  __shared__ u16 sAh[4096], sAl[4096], sW[4096];
  const int tid = threadIdx.x;
  const int lane = tid & 63, wv = tid >> 6;
  const int nl = lane & 15, kq = lane >> 4;
  const int m0 = blockIdx.y*128, n0 = blockIdx.x*128;
  const int wm16 = (wv>>1)*4, wn16 = (wv&1)*4;   // tile indices /16

  f32x4 acc[4][4];
  #pragma unroll
  for (int mi=0;mi<4;mi++)
    #pragma unroll
    for (int ni=0;ni<4;ni++) acc[mi][ni] = (f32x4){0.f,0.f,0.f,0.f};

  for (int k0=0; k0<K; k0+=32){
    #pragma unroll
    for (int it=0; it<2; it++){
      int c = tid + it*256;
      int row = c >> 2, q = c & 3;
      int ldsoff = ((row>>4)*64 + q*16 + (row&15))*8;
      bf16x8 h = (bf16x8){0,0,0,0,0,0,0,0}, l = (bf16x8){0,0,0,0,0,0,0,0};
      if (m0 + row < M){
        size_t ga = (size_t)(m0+row)*K + k0 + q*8;
        float4 a0 = *reinterpret_cast<const float4*>(&Af[ga]);
        float4 a1 = *reinterpret_cast<const float4*>(&Af[ga+4]);
        float av[8] = {a0.x,a0.y,a0.z,a0.w,a1.x,a1.y,a1.z,a1.w};
        #pragma unroll
        for (int e=0;e<8;e++){
          short hb = f2bf(av[e]);
          h[e] = hb;
          l[e] = f2bf(av[e] - bf2f(hb));
        }
      }
      *reinterpret_cast<bf16x8*>(&sAh[ldsoff]) = h;
      *reinterpret_cast<bf16x8*>(&sAl[ldsoff]) = l;
      size_t gw = (size_t)(n0+row)*K + k0 + q*8;
      *reinterpret_cast<uint4*>(&sW[ldsoff]) = *reinterpret_cast<const uint4*>(&Wb[gw]);
    }
    __syncthreads();
    bf16x8 ah[4], al[4], wr[4];
    #pragma unroll
    for (int mi=0;mi<4;mi++){
      int off = ((wm16+mi)*64 + kq*16 + nl)*8;
      ah[mi] = *reinterpret_cast<const bf16x8*>(&sAh[off]);
      al[mi] = *reinterpret_cast<const bf16x8*>(&sAl[off]);
    }
    #pragma unroll
    for (int ni=0;ni<4;ni++){
      int off = ((wn16+ni)*64 + kq*16 + nl)*8;
      wr[ni] = *reinterpret_cast<const bf16x8*>(&sW[off]);
    }
    #pragma unroll
    for (int mi=0;mi<4;mi++)
      #pragma unroll
      for (int ni=0;ni<4;ni++){
        acc[mi][ni] = __builtin_amdgcn_mfma_f32_16x16x32_bf16(ah[mi], wr[ni], acc[mi][ni], 0, 0, 0);
        acc[mi][ni] = __builtin_amdgcn_mfma_f32_16x16x32_bf16(al[mi], wr[ni], acc[mi][ni], 0, 0, 0);
      }
    __syncthreads();
  }
  // epilogue: D col = nl, row = kq*4 + r within tile
  #pragma unroll
  for (int mi=0;mi<4;mi++){
    #pragma unroll
    for (int ni=0;ni<4;ni++){
      int col = n0 + (wn16+ni)*16 + nl;
      float bv = bias ? bias[col] : 0.0f;
      #pragma unroll
      for (int r2=0;r2<4;r2++){
        int rrow = m0 + (wm16+mi)*16 + kq*4 + r2;
        if (rrow >= M) continue;
        float val = acc[mi][ni][r2] + bv;
        if (EP==1) val = msrc[(size_t)rrow*N + col] * sigm(val);
        C[(size_t)rrow*N + col] = val;
      }
    }
  }
}

// one block per (p,b): scores over q (tanh attention), softmax over q, ct, concat write
__global__ __launch_bounds__(256) void attn_k(const float* __restrict__ Qh, const float* __restrict__ Ph,
   const float* __restrict__ qrep, const float* __restrict__ prep, const float* __restrict__ v,
   const float* __restrict__ qmask, float* __restrict__ xcat)
{
  int p = blockIdx.x, b = blockIdx.y;
  int tid = threadIdx.x;
  __shared__ float ph[HH];
  __shared__ float vv[HH];
  __shared__ float sc[64];
  size_t pb = (size_t)p*BB + b;
  ph[tid] = Ph[pb*HH + tid];
  vv[tid] = v[tid];
  xcat[pb*512 + tid] = prep[pb*II + tid];
  __syncthreads();
  int wid = tid >> 6, lane = tid & 63;
  for (int q = wid; q < TPQ; q += 4){
    const float* qh = Qh + ((size_t)q*BB + b)*HH;
    float s = 0.0f;
    for (int hh = lane; hh < HH; hh += 64)
      s += vv[hh]*tanhfast(qh[hh] + ph[hh]);
    #pragma unroll
    for (int off=32; off>0; off>>=1) s += __shfl_xor(s, off);
    if (lane==0) sc[q] = s;
  }
  __syncthreads();
  if (wid==0){
    float m = (lane < TPQ) ? qmask[lane*BB + b] : 0.0f;
    float val = (lane < TPQ) ? (m*sc[lane] + (1.0f-m)*(-1e30f)) : -INFINITY;
    float mx = val;
    #pragma unroll
    for (int off=32; off>0; off>>=1) mx = fmaxf(mx, __shfl_xor(mx, off));
    float e = (lane < TPQ) ? __expf(val - mx) : 0.0f;
    float sum = e;
    #pragma unroll
    for (int off=32; off>0; off>>=1) sum += __shfl_xor(sum, off);
    if (lane < TPQ) sc[lane] = e / sum;
  }
  __syncthreads();
  float acc = 0.0f;
  for (int q=0;q<TPQ;q++)
    acc += sc[q] * qrep[((size_t)q*BB + b)*II + tid];
  xcat[pb*512 + 256 + tid] = acc;
}

// ---------------------------------------------------------------------------
// Persistent MFMA GRU scan (R10 proven body, MFMA order gg-MAJOR).
// grid = 32 (b,dir), block = 512. Full Whh (bf16) in regs. h: 256-bf16
// ping-pong LDS broadcast. Scalar per-step address recompute + store-in-
// epilogue (proven fast; pointer-increment & deferred-store both regressed).
// KEY CHANGE vs R10: MFMAs ordered gg-major (24 for gg=0, then 24 for gg=1)
// so acc[0][*] completes halfway through the stream -> the gg=0 epilogue's
// dependent VALU chain can issue while the gg=1 MFMAs drain the matrix pipe.
// (In ks-major order every acc completed only in the last 6 MFMAs, forcing
// the whole epilogue to serialize after the 1862-cyc pipe drain.)
// ---------------------------------------------------------------------------
__global__ __launch_bounds__(512) void gru_scan_mfma(
    const float* __restrict__ xg,    // [TPP][16][1536]
    const float* __restrict__ Whh,   // [2][768][256]
    const float* __restrict__ bhh,   // [2][768]
    float* __restrict__ out)         // [TPP][16][512]
{
  __shared__ u16 hbuf[2][256];

  const int b   = blockIdx.x & 15;
  const int dir = blockIdx.x >> 4;
  const int tid  = threadIdx.x;
  const int wv   = tid >> 6;
  const int lane = tid & 63;
  const int nl   = lane & 15;
  const int kq   = lane >> 4;

  ((u16*)hbuf)[tid] = 0;

  // Whh fragments bf16, all in registers. 16x16x32 B layout: n=lane&15, k=ks*32+kq*8+e
  bf16x8 wreg[8][6];
  #pragma unroll
  for (int ks=0; ks<8; ks++){
    #pragma unroll
    for (int gg=0; gg<2; gg++){
      #pragma unroll
      for (int gi=0; gi<3; gi++){
        int nrow = gi*256 + wv*32 + gg*16 + nl;
        const float* wsrc = Whh + (size_t)dir*768*256 + (size_t)nrow*256 + ks*32 + kq*8;
        float4 lo = *reinterpret_cast<const float4*>(wsrc);
        float4 hi = *reinterpret_cast<const float4*>(wsrc+4);
        bf16x8 f;
        f[0]=f2bf(lo.x); f[1]=f2bf(lo.y); f[2]=f2bf(lo.z); f[3]=f2bf(lo.w);
        f[4]=f2bf(hi.x); f[5]=f2bf(hi.y); f[6]=f2bf(hi.z); f[7]=f2bf(hi.w);
        wreg[ks][gg*3+gi] = f;
      }
    }
  }

  float bias[2][3];
  #pragma unroll
  for (int gg=0; gg<2; gg++)
    #pragma unroll
    for (int gi=0; gi<3; gi++)
      bias[gg][gi] = bhh[dir*768 + gi*256 + wv*32 + gg*16 + nl];

  // lane's xg column base: dir*768 + gi*256 + (wv*32 + gg*16 + nl)
  const float* xb = xg + dir*768 + wv*32 + nl;

  float hold[2] = {0.0f, 0.0f};

  __syncthreads();

  #pragma unroll 1
  for (int s=0; s<TPP; s++){
    const int t = dir ? (TPP-1-s) : s;

    // xg values for this step (consumed in epilogue; latency hides under MFMA)
    float xv[2][3];
    {
      size_t ro = (size_t)(t*16 + b)*1536;
      #pragma unroll
      for (int gg=0; gg<2; gg++)
        #pragma unroll
        for (int gi=0; gi<3; gi++)
          xv[gg][gi] = xb[ro + gi*256 + gg*16];
    }

    f32x4 acc[2][3];
    #pragma unroll
    for (int gg=0; gg<2; gg++)
      #pragma unroll
      for (int gi=0; gi<3; gi++)
        acc[gg][gi] = (f32x4){0.f,0.f,0.f,0.f};

    // A frags: broadcast h (bf16), all 8 reads up-front
    const char* hp = (const char*)hbuf[s&1];
    bf16x8 a[8];
    #pragma unroll
    for (int ks=0; ks<8; ks++)
      a[ks] = *reinterpret_cast<const bf16x8*>(hp + ks*64 + kq*16);

    // gg-MAJOR MFMA order: gg=0 tiles complete early
    #pragma unroll
    for (int ks=0; ks<8; ks++){
      #pragma unroll
      for (int gi=0; gi<3; gi++)
        acc[0][gi] = __builtin_amdgcn_mfma_f32_16x16x32_bf16(a[ks], wreg[ks][gi], acc[0][gi], 0, 0, 0);
    }
    #pragma unroll
    for (int ks=0; ks<8; ks++){
      #pragma unroll
      for (int gi=0; gi<3; gi++)
        acc[1][gi] = __builtin_amdgcn_mfma_f32_16x16x32_bf16(a[ks], wreg[ks][3+gi], acc[1][gi], 0, 0, 0);
    }

    // epilogue: D row 0 lives in lanes 0..15, reg 0.
    // gg=0 epilogue depends only on acc[0][*] -> can overlap gg=1 pipe drain.
    if (lane < 16){
      u16* wb = hbuf[(s&1)^1];
      #pragma unroll
      for (int gg=0; gg<2; gg++){
        int j = wv*32 + gg*16 + nl;
        float r = sigm(xv[gg][0] + acc[gg][0][0] + bias[gg][0]);
        float z = sigm(xv[gg][1] + acc[gg][1][0] + bias[gg][1]);
        float n = tanhfast(xv[gg][2] + r*(acc[gg][2][0] + bias[gg][2]));
        float hv = (1.0f - z)*n + z*hold[gg];
        hold[gg] = hv;
        wb[j] = (u16)f2bf(hv);
        out[(size_t)(t*16 + b)*512 + dir*256 + j] = hv;
      }
    }
    __syncthreads();   // new h visible before next step's A reads
  }
}

extern "C" void kernel_launch(void* const* d_in, const int* in_sizes, int n_in,
                              void* d_out, int out_size, void* d_ws, size_t ws_size,
                              hipStream_t stream)
{
  const float* prep  = (const float*)d_in[0];
  const float* qrep  = (const float*)d_in[1];
  const float* qmask = (const float*)d_in[3];
  const float* WuQ   = (const float*)d_in[4];
  const float* WuP   = (const float*)d_in[5];
  const float* v     = (const float*)d_in[6];
  const float* Wg    = (const float*)d_in[7];
  const float* Wih   = (const float*)d_in[8];
  const float* Whh   = (const float*)d_in[9];
  const float* bih   = (const float*)d_in[10];
  const float* bhh   = (const float*)d_in[11];
  float* out = (float*)d_out;

  float* ws = (float*)d_ws;
  size_t off = 0;
  float* Qh   = ws + off; off += (size_t)TPQ*BB*HH;
  float* Ph   = ws + off; off += (size_t)TPP*BB*HH;
  float* xcat = ws + off; off += (size_t)TPP*BB*512;
  float* ybuf = ws + off; off += (size_t)TPP*BB*512;
  float* xg   = ws + off; off += (size_t)TPP*BB*1536;
  u16*  Wb    = (u16*)(ws + off); off += (size_t)3*1536*512/2;
  u16*  Wgb   = (u16*)(ws + off); off += (size_t)512*512/2;
  u16*  Wqb   = (u16*)(ws + off); off += (size_t)256*256/2;
  u16*  Wpb   = (u16*)(ws + off); off += (size_t)256*256/2;

  {
    int n = 3*1536*512;
    f2bf_k<<<dim3((n+255)/256), dim3(256), 0, stream>>>(Wih, Wb, n);
    n = 512*512;
    f2bf_k<<<dim3((n+255)/256), dim3(256), 0, stream>>>(Wg, Wgb, n);
    n = 256*256;
    f2bf_k<<<dim3((n+255)/256), dim3(256), 0, stream>>>(WuQ, Wqb, n);
    f2bf_k<<<dim3((n+255)/256), dim3(256), 0, stream>>>(WuP, Wpb, n);
  }

  // Qh = question @ WuQ.T : M=960, N=256, K=256 (natural [N][K] weight layout)
  gemm_bf16_hl<0><<<dim3(2, 8), dim3(256), 0, stream>>>(qrep, Wqb, nullptr, nullptr, Qh, TPQ*BB, 256, 256);
  // Ph = passage @ WuP.T : M=6400
  gemm_bf16_hl<0><<<dim3(2, 50), dim3(256), 0, stream>>>(prep, Wpb, nullptr, nullptr, Ph, TPP*BB, 256, 256);
  // attention + concat
  attn_k<<<dim3(TPP, BB), dim3(256), 0, stream>>>(Qh, Ph, qrep, prep, v, qmask, xcat);
  // gate: ybuf = xcat * sigmoid(xcat @ Wg.T)  via bf16 MFMA
  gemm_bf16_hl<1><<<dim3(4, 50), dim3(256), 0, stream>>>(xcat, Wgb, nullptr, xcat, ybuf, TPP*BB, 512, 512);

  float* cur = ybuf;
  float* nxt = xcat;
  for (int l=0;l<3;l++){
    // xg = cur @ Wih[l].T + bih[l]  via bf16 MFMA (A hi/lo split in staging)
    gemm_bf16_hl<0><<<dim3(12, 50), dim3(256), 0, stream>>>(cur, Wb + (size_t)l*1536*512,
                                                            bih + (size_t)l*1536, nullptr, xg, TPP*BB, 1536, 512);
    float* o = (l==2) ? out : nxt;
    gru_scan_mfma<<<dim3(32), dim3(512), 0, stream>>>(xg, Whh + (size_t)l*2*768*256,
                                                      bhh + (size_t)l*2*768, o);
    float* tmp = cur; cur = o; nxt = tmp;
  }
}

// Round 13
// 2033.437 us; speedup vs baseline: 1.1588x; 1.1588x over previous
//
#include <hip/hip_runtime.h>
#include <math.h>

#define TPQ 60
#define TPP 400
#define BB  16
#define II  256
#define HH  256

typedef short bf16x8 __attribute__((ext_vector_type(8)));
typedef float f32x4  __attribute__((ext_vector_type(4)));
typedef unsigned short u16;

__device__ __forceinline__ float sigm(float x){ return 1.0f/(1.0f+__expf(-x)); }
__device__ __forceinline__ float tanhfast(float x){
  x = fminf(fmaxf(x,-20.0f),20.0f);
  float t = __expf(2.0f*x);
  return (t-1.0f)/(t+1.0f);
}
__device__ __forceinline__ short f2bf(float f){
  unsigned u = __float_as_uint(f);
  unsigned r = (u + 0x7fffu + ((u>>16)&1u)) >> 16;
  return (short)r;
}
__device__ __forceinline__ float bf2f(short h){
  return __uint_as_float(((unsigned)(unsigned short)h)<<16);
}

__global__ void f2bf_k(const float* __restrict__ src, u16* __restrict__ dst, int n){
  int i = blockIdx.x*256 + threadIdx.x;
  if (i < n) dst[i] = (u16)f2bf(src[i]);
}

// ---------------------------------------------------------------------------
// bf16 MFMA GEMM, A supplied as f32 and hi/lo-split during LDS staging:
//   C[M][N] = A[M][K] @ W[N][K]^T (+bias)   EP==1: C = msrc * sigmoid(C)
// tile 128x128, K-step 32, 256 threads (4 waves, 2x2 quadrants of 64x64).
// LDS in fragment order -> staging writes and fragment reads conflict-free.
// Requires N%128==0, K%32==0; M guarded.
// ---------------------------------------------------------------------------
template<int EP>
__global__ __launch_bounds__(256) void gemm_bf16_hl(
    const float* __restrict__ Af,   // [M][K] f32
    const u16* __restrict__ Wb,     // [N][K] bf16
    const float* __restrict__ bias, // [N]
    const float* __restrict__ msrc, // [M][N] (EP==1)
    float* __restrict__ C, int M, int N, int K)
{
  __shared__ u16 sAh[4096], sAl[4096], sW[4096];
  const int tid = threadIdx.x;
  const int lane = tid & 63, wv = tid >> 6;
  const int nl = lane & 15, kq = lane >> 4;
  const int m0 = blockIdx.y*128, n0 = blockIdx.x*128;
  const int wm16 = (wv>>1)*4, wn16 = (wv&1)*4;   // tile indices /16

  f32x4 acc[4][4];
  #pragma unroll
  for (int mi=0;mi<4;mi++)
    #pragma unroll
    for (int ni=0;ni<4;ni++) acc[mi][ni] = (f32x4){0.f,0.f,0.f,0.f};

  for (int k0=0; k0<K; k0+=32){
    #pragma unroll
    for (int it=0; it<2; it++){
      int c = tid + it*256;
      int row = c >> 2, q = c & 3;
      int ldsoff = ((row>>4)*64 + q*16 + (row&15))*8;
      bf16x8 h = (bf16x8){0,0,0,0,0,0,0,0}, l = (bf16x8){0,0,0,0,0,0,0,0};
      if (m0 + row < M){
        size_t ga = (size_t)(m0+row)*K + k0 + q*8;
        float4 a0 = *reinterpret_cast<const float4*>(&Af[ga]);
        float4 a1 = *reinterpret_cast<const float4*>(&Af[ga+4]);
        float av[8] = {a0.x,a0.y,a0.z,a0.w,a1.x,a1.y,a1.z,a1.w};
        #pragma unroll
        for (int e=0;e<8;e++){
          short hb = f2bf(av[e]);
          h[e] = hb;
          l[e] = f2bf(av[e] - bf2f(hb));
        }
      }
      *reinterpret_cast<bf16x8*>(&sAh[ldsoff]) = h;
      *reinterpret_cast<bf16x8*>(&sAl[ldsoff]) = l;
      size_t gw = (size_t)(n0+row)*K + k0 + q*8;
      *reinterpret_cast<uint4*>(&sW[ldsoff]) = *reinterpret_cast<const uint4*>(&Wb[gw]);
    }
    __syncthreads();
    bf16x8 ah[4], al[4], wr[4];
    #pragma unroll
    for (int mi=0;mi<4;mi++){
      int off = ((wm16+mi)*64 + kq*16 + nl)*8;
      ah[mi] = *reinterpret_cast<const bf16x8*>(&sAh[off]);
      al[mi] = *reinterpret_cast<const bf16x8*>(&sAl[off]);
    }
    #pragma unroll
    for (int ni=0;ni<4;ni++){
      int off = ((wn16+ni)*64 + kq*16 + nl)*8;
      wr[ni] = *reinterpret_cast<const bf16x8*>(&sW[off]);
    }
    #pragma unroll
    for (int mi=0;mi<4;mi++)
      #pragma unroll
      for (int ni=0;ni<4;ni++){
        acc[mi][ni] = __builtin_amdgcn_mfma_f32_16x16x32_bf16(ah[mi], wr[ni], acc[mi][ni], 0, 0, 0);
        acc[mi][ni] = __builtin_amdgcn_mfma_f32_16x16x32_bf16(al[mi], wr[ni], acc[mi][ni], 0, 0, 0);
      }
    __syncthreads();
  }
  // epilogue: D col = nl, row = kq*4 + r within tile
  #pragma unroll
  for (int mi=0;mi<4;mi++){
    #pragma unroll
    for (int ni=0;ni<4;ni++){
      int col = n0 + (wn16+ni)*16 + nl;
      float bv = bias ? bias[col] : 0.0f;
      #pragma unroll
      for (int r2=0;r2<4;r2++){
        int rrow = m0 + (wm16+mi)*16 + kq*4 + r2;
        if (rrow >= M) continue;
        float val = acc[mi][ni][r2] + bv;
        if (EP==1) val = msrc[(size_t)rrow*N + col] * sigm(val);
        C[(size_t)rrow*N + col] = val;
      }
    }
  }
}

// one block per (p,b): scores over q (tanh attention), softmax over q, ct, concat write
__global__ __launch_bounds__(256) void attn_k(const float* __restrict__ Qh, const float* __restrict__ Ph,
   const float* __restrict__ qrep, const float* __restrict__ prep, const float* __restrict__ v,
   const float* __restrict__ qmask, float* __restrict__ xcat)
{
  int p = blockIdx.x, b = blockIdx.y;
  int tid = threadIdx.x;
  __shared__ float ph[HH];
  __shared__ float vv[HH];
  __shared__ float sc[64];
  size_t pb = (size_t)p*BB + b;
  ph[tid] = Ph[pb*HH + tid];
  vv[tid] = v[tid];
  xcat[pb*512 + tid] = prep[pb*II + tid];
  __syncthreads();
  int wid = tid >> 6, lane = tid & 63;
  for (int q = wid; q < TPQ; q += 4){
    const float* qh = Qh + ((size_t)q*BB + b)*HH;
    float s = 0.0f;
    for (int hh = lane; hh < HH; hh += 64)
      s += vv[hh]*tanhfast(qh[hh] + ph[hh]);
    #pragma unroll
    for (int off=32; off>0; off>>=1) s += __shfl_xor(s, off);
    if (lane==0) sc[q] = s;
  }
  __syncthreads();
  if (wid==0){
    float m = (lane < TPQ) ? qmask[lane*BB + b] : 0.0f;
    float val = (lane < TPQ) ? (m*sc[lane] + (1.0f-m)*(-1e30f)) : -INFINITY;
    float mx = val;
    #pragma unroll
    for (int off=32; off>0; off>>=1) mx = fmaxf(mx, __shfl_xor(mx, off));
    float e = (lane < TPQ) ? __expf(val - mx) : 0.0f;
    float sum = e;
    #pragma unroll
    for (int off=32; off>0; off>>=1) sum += __shfl_xor(sum, off);
    if (lane < TPQ) sc[lane] = e / sum;
  }
  __syncthreads();
  float acc = 0.0f;
  for (int q=0;q<TPQ;q++)
    acc += sc[q] * qrep[((size_t)q*BB + b)*II + tid];
  xcat[pb*512 + 256 + tid] = acc;
}

// ---------------------------------------------------------------------------
// Persistent MFMA GRU scan (R10 proven body + quadrant-split epilogue).
// grid = 32 (b,dir), block = 512. Full Whh (bf16) in regs. h: 256-bf16
// ping-pong LDS broadcast. Scalar per-step address recompute + store-in-
// epilogue (proven fast; pointer-increment / deferred-store / gg-major all
// measured regressions or null -- do not change).
// KEY FACT exploited: A (h) is broadcast across all 16 M rows, so every D
// row is bitwise identical -> each lane quadrant holds the complete gate
// vector. Epilogue now splits by quadrant: lanes 0-15 (kq=0) compute gate
// group 0, lanes 16-31 (kq=1) compute gate group 1 from their own acc copy.
// Halves epilogue VALU issue; xv/bias loads drop 6->3 per lane.
// ---------------------------------------------------------------------------
__global__ __launch_bounds__(512) void gru_scan_mfma(
    const float* __restrict__ xg,    // [TPP][16][1536]
    const float* __restrict__ Whh,   // [2][768][256]
    const float* __restrict__ bhh,   // [2][768]
    float* __restrict__ out)         // [TPP][16][512]
{
  __shared__ u16 hbuf[2][256];

  const int b   = blockIdx.x & 15;
  const int dir = blockIdx.x >> 4;
  const int tid  = threadIdx.x;
  const int wv   = tid >> 6;
  const int lane = tid & 63;
  const int nl   = lane & 15;
  const int kq   = lane >> 4;
  const int ggl  = kq & 1;          // this lane's gate-group in the epilogue

  ((u16*)hbuf)[tid] = 0;

  // Whh fragments bf16, all in registers. 16x16x32 B layout: n=lane&15, k=ks*32+kq*8+e
  bf16x8 wreg[8][6];
  #pragma unroll
  for (int ks=0; ks<8; ks++){
    #pragma unroll
    for (int gg=0; gg<2; gg++){
      #pragma unroll
      for (int gi=0; gi<3; gi++){
        int nrow = gi*256 + wv*32 + gg*16 + nl;
        const float* wsrc = Whh + (size_t)dir*768*256 + (size_t)nrow*256 + ks*32 + kq*8;
        float4 lo = *reinterpret_cast<const float4*>(wsrc);
        float4 hi = *reinterpret_cast<const float4*>(wsrc+4);
        bf16x8 f;
        f[0]=f2bf(lo.x); f[1]=f2bf(lo.y); f[2]=f2bf(lo.z); f[3]=f2bf(lo.w);
        f[4]=f2bf(hi.x); f[5]=f2bf(hi.y); f[6]=f2bf(hi.z); f[7]=f2bf(hi.w);
        wreg[ks][gg*3+gi] = f;
      }
    }
  }

  // per-lane (quadrant-split) bias for this lane's gate-group columns
  float bias3[3];
  #pragma unroll
  for (int gi=0; gi<3; gi++)
    bias3[gi] = bhh[dir*768 + gi*256 + wv*32 + ggl*16 + nl];

  // lane's xg column base for ITS gate-group: dir*768 + gi*256 + (wv*32 + ggl*16 + nl)
  const float* xb = xg + dir*768 + wv*32 + ggl*16 + nl;

  float hold = 0.0f;   // this lane's own h (col wv*32 + ggl*16 + nl)

  __syncthreads();

  #pragma unroll 1
  for (int s=0; s<TPP; s++){
    const int t = dir ? (TPP-1-s) : s;

    // xg values for this step (3 per lane; consumed in epilogue)
    float xv[3];
    {
      size_t ro = (size_t)(t*16 + b)*1536;
      #pragma unroll
      for (int gi=0; gi<3; gi++)
        xv[gi] = xb[ro + gi*256];
    }

    f32x4 acc[2][3];
    #pragma unroll
    for (int gg=0; gg<2; gg++)
      #pragma unroll
      for (int gi=0; gi<3; gi++)
        acc[gg][gi] = (f32x4){0.f,0.f,0.f,0.f};

    // A frags: broadcast h (bf16), all 8 reads up-front
    const char* hp = (const char*)hbuf[s&1];
    bf16x8 a[8];
    #pragma unroll
    for (int ks=0; ks<8; ks++)
      a[ks] = *reinterpret_cast<const bf16x8*>(hp + ks*64 + kq*16);
    #pragma unroll
    for (int ks=0; ks<8; ks++){
      #pragma unroll
      for (int gg=0; gg<2; gg++)
        #pragma unroll
        for (int gi=0; gi<3; gi++)
          acc[gg][gi] = __builtin_amdgcn_mfma_f32_16x16x32_bf16(a[ks], wreg[ks][gg*3+gi], acc[gg][gi], 0, 0, 0);
    }

    // epilogue, quadrant-split: every lane's acc rows are identical (broadcast
    // A), so lane quadrant kq=0 uses acc[0][*][0], kq=1 uses acc[1][*][0].
    if (lane < 32){
      u16* wb = hbuf[(s&1)^1];
      int j = wv*32 + ggl*16 + nl;
      float a0 = ggl ? acc[1][0][0] : acc[0][0][0];
      float a1 = ggl ? acc[1][1][0] : acc[0][1][0];
      float a2 = ggl ? acc[1][2][0] : acc[0][2][0];
      float r = sigm(xv[0] + a0 + bias3[0]);
      float z = sigm(xv[1] + a1 + bias3[1]);
      float n = tanhfast(xv[2] + r*(a2 + bias3[2]));
      float hv = (1.0f - z)*n + z*hold;
      hold = hv;
      wb[j] = (u16)f2bf(hv);
      out[(size_t)(t*16 + b)*512 + dir*256 + j] = hv;
    }
    __syncthreads();   // new h visible before next step's A reads
  }
}

extern "C" void kernel_launch(void* const* d_in, const int* in_sizes, int n_in,
                              void* d_out, int out_size, void* d_ws, size_t ws_size,
                              hipStream_t stream)
{
  const float* prep  = (const float*)d_in[0];
  const float* qrep  = (const float*)d_in[1];
  const float* qmask = (const float*)d_in[3];
  const float* WuQ   = (const float*)d_in[4];
  const float* WuP   = (const float*)d_in[5];
  const float* v     = (const float*)d_in[6];
  const float* Wg    = (const float*)d_in[7];
  const float* Wih   = (const float*)d_in[8];
  const float* Whh   = (const float*)d_in[9];
  const float* bih   = (const float*)d_in[10];
  const float* bhh   = (const float*)d_in[11];
  float* out = (float*)d_out;

  float* ws = (float*)d_ws;
  size_t off = 0;
  float* Qh   = ws + off; off += (size_t)TPQ*BB*HH;
  float* Ph   = ws + off; off += (size_t)TPP*BB*HH;
  float* xcat = ws + off; off += (size_t)TPP*BB*512;
  float* ybuf = ws + off; off += (size_t)TPP*BB*512;
  float* xg   = ws + off; off += (size_t)TPP*BB*1536;
  u16*  Wb    = (u16*)(ws + off); off += (size_t)3*1536*512/2;
  u16*  Wgb   = (u16*)(ws + off); off += (size_t)512*512/2;
  u16*  Wqb   = (u16*)(ws + off); off += (size_t)256*256/2;
  u16*  Wpb   = (u16*)(ws + off); off += (size_t)256*256/2;

  {
    int n = 3*1536*512;
    f2bf_k<<<dim3((n+255)/256), dim3(256), 0, stream>>>(Wih, Wb, n);
    n = 512*512;
    f2bf_k<<<dim3((n+255)/256), dim3(256), 0, stream>>>(Wg, Wgb, n);
    n = 256*256;
    f2bf_k<<<dim3((n+255)/256), dim3(256), 0, stream>>>(WuQ, Wqb, n);
    f2bf_k<<<dim3((n+255)/256), dim3(256), 0, stream>>>(WuP, Wpb, n);
  }

  // Qh = question @ WuQ.T : M=960, N=256, K=256 (natural [N][K] weight layout)
  gemm_bf16_hl<0><<<dim3(2, 8), dim3(256), 0, stream>>>(qrep, Wqb, nullptr, nullptr, Qh, TPQ*BB, 256, 256);
  // Ph = passage @ WuP.T : M=6400
  gemm_bf16_hl<0><<<dim3(2, 50), dim3(256), 0, stream>>>(prep, Wpb, nullptr, nullptr, Ph, TPP*BB, 256, 256);
  // attention + concat
  attn_k<<<dim3(TPP, BB), dim3(256), 0, stream>>>(Qh, Ph, qrep, prep, v, qmask, xcat);
  // gate: ybuf = xcat * sigmoid(xcat @ Wg.T)  via bf16 MFMA
  gemm_bf16_hl<1><<<dim3(4, 50), dim3(256), 0, stream>>>(xcat, Wgb, nullptr, xcat, ybuf, TPP*BB, 512, 512);

  float* cur = ybuf;
  float* nxt = xcat;
  for (int l=0;l<3;l++){
    // xg = cur @ Wih[l].T + bih[l]  via bf16 MFMA (A hi/lo split in staging)
    gemm_bf16_hl<0><<<dim3(12, 50), dim3(256), 0, stream>>>(cur, Wb + (size_t)l*1536*512,
                                                            bih + (size_t)l*1536, nullptr, xg, TPP*BB, 1536, 512);
    float* o = (l==2) ? out : nxt;
    gru_scan_mfma<<<dim3(32), dim3(512), 0, stream>>>(xg, Whh + (size_t)l*2*768*256,
                                                      bhh + (size_t)l*2*768, o);
    float* tmp = cur; cur = o; nxt = tmp;
  }
}